// Round 1
// baseline (2164.367 us; speedup 1.0000x reference)
//
#include <hip/hip_runtime.h>
#include <math.h>

// Problem constants
constexpr int Bn  = 128;   // batch
constexpr int Tn  = 2048;  // time
constexpr int FCn = 512;   // context feats (g)
constexpr int FXn = 512;   // encoding feats (x)
constexpr int STR = 136;   // LDS row stride in bf16 elems (128 + 8 pad, 16B-aligned rows)

typedef __attribute__((ext_vector_type(8))) short  bf16x8;
typedef __attribute__((ext_vector_type(4))) float  f32x4;

__device__ __forceinline__ unsigned short f2bf(float f) {
  unsigned int u = __float_as_uint(f);
  return (unsigned short)((u + 0x7FFFu + ((u >> 16) & 1u)) >> 16);  // RNE
}

// convert 8 consecutive fp32 -> 8 bf16, one 16B LDS store
__device__ __forceinline__ void stage8(unsigned short* dst, const float* src) {
  const float4* s4 = reinterpret_cast<const float4*>(src);
  float4 a = s4[0], b = s4[1];
  union { unsigned short u[8]; uint4 v; } p;
  p.u[0] = f2bf(a.x); p.u[1] = f2bf(a.y); p.u[2] = f2bf(a.z); p.u[3] = f2bf(a.w);
  p.u[4] = f2bf(b.x); p.u[5] = f2bf(b.y); p.u[6] = f2bf(b.z); p.u[7] = f2bf(b.w);
  *reinterpret_cast<uint4*>(dst) = p.v;
}

__global__ void zero4(float* out) {
  if (threadIdx.x < 4) out[threadIdx.x] = 0.0f;
}

__global__ void finalize4(float* out) {
  int k = threadIdx.x;
  if (k < 4) out[k] *= 1.0f / (128.0f * (float)(Tn - (1 << k)));
}

// One block per (k, t). Computes Z[i,j] = sum_g C[i,t,g] * (sum_x W[k,g,x] X[j,t+tau,x])
// (bias dropped: cancels in Zdiag - lse), then row-wise lse over j and the
// (Zdiag - lse) partial sum, atomically accumulated into out[k].
__global__ __launch_bounds__(512, 2)
void infonce_main(const float* __restrict__ Cp, const float* __restrict__ Xp,
                  const float* __restrict__ Wp, float* __restrict__ out)
{
  __shared__ __align__(16) unsigned char smem[4 * 128 * STR * 2];  // 139264 B
  unsigned short* sX = (unsigned short*)(smem);                    // [128][STR] X chunk (j,x)
  unsigned short* sW = (unsigned short*)(smem + 1 * 128 * STR * 2);// [128][STR] W chunk (g,x)
  unsigned short* sC = (unsigned short*)(smem + 2 * 128 * STR * 2);// [128][STR] C chunk (i,g)
  unsigned short* sY = (unsigned short*)(smem + 3 * 128 * STR * 2);// [128][STR] Y chunk (j,g)
  float* sZ   = (float*)(smem);                                    // [128][132] fp32, overlays sX+sW
  float* sRed = (float*)(smem + 3 * 128 * STR * 2);                // 8 floats, overlays sY

  const int tid  = threadIdx.x;
  const int lane = tid & 63;
  const int wave = tid >> 6;     // 0..7
  const int r    = lane & 15;
  const int h    = lane >> 4;    // 0..3
  const int wr   = wave >> 1;    // 0..3  (32-row group)
  const int wc   = wave & 1;     // 0..1  (64-col group)

  const int bx = blockIdx.x;
  const int k  = bx & 3;
  const int t  = bx >> 2;
  const int tau = 1 << k;        // TAU = {1,2,4,8}
  if (t >= Tn - tau) return;     // uniform early-exit, before any barrier
  const int s = t + tau;

  const float* Cbase = Cp + (size_t)t * FCn;            // C[i,t,g] = Cbase[i*Tn*FCn + g]
  const float* Xbase = Xp + (size_t)s * FXn;            // X[j,s,x] = Xbase[j*Tn*FXn + x]
  const float* Wbase = Wp + (size_t)k * FCn * FXn;      // W[k,g,x]

  f32x4 zacc[2][4];
#pragma unroll
  for (int a = 0; a < 2; ++a)
#pragma unroll
    for (int b = 0; b < 4; ++b) zacc[a][b] = f32x4{0.f, 0.f, 0.f, 0.f};

  for (int gc = 0; gc < 4; ++gc) {
    __syncthreads();  // prev Z-phase reads of sC done before restaging
    // stage C chunk: sC[i][gg] = bf16(C[i, t, gc*128+gg])
#pragma unroll
    for (int rep = 0; rep < 4; ++rep) {
      int lin = rep * 4096 + tid * 8;
      int i = lin >> 7, gg = lin & 127;
      stage8(sC + i * STR + gg, Cbase + (size_t)i * (Tn * FCn) + gc * 128 + gg);
    }

    f32x4 yacc[2][4];
#pragma unroll
    for (int a = 0; a < 2; ++a)
#pragma unroll
      for (int b = 0; b < 4; ++b) yacc[a][b] = f32x4{0.f, 0.f, 0.f, 0.f};

    for (int xc = 0; xc < 4; ++xc) {
      __syncthreads();  // prev MFMA reads of sX/sW done
#pragma unroll
      for (int rep = 0; rep < 4; ++rep) {
        int lin = rep * 4096 + tid * 8;
        int j = lin >> 7, xx = lin & 127;
        stage8(sX + j * STR + xx, Xbase + (size_t)j * (Tn * FXn) + xc * 128 + xx);
      }
#pragma unroll
      for (int rep = 0; rep < 4; ++rep) {
        int lin = rep * 4096 + tid * 8;
        int gg = lin >> 7, xx = lin & 127;
        stage8(sW + gg * STR + xx, Wbase + (size_t)(gc * 128 + gg) * FXn + xc * 128 + xx);
      }
      __syncthreads();
      // Y-GEMM: Y[j,g] += X[j,x] * W[g,x], wave tile 32(j) x 64(g), K-chunk 128
#pragma unroll
      for (int ks = 0; ks < 4; ++ks) {
        const int xo = ks * 32 + h * 8;
        bf16x8 a0 = *(const bf16x8*)(sX + (wr * 32 + 0  + r) * STR + xo);
        bf16x8 a1 = *(const bf16x8*)(sX + (wr * 32 + 16 + r) * STR + xo);
#pragma unroll
        for (int bg = 0; bg < 4; ++bg) {
          bf16x8 bb = *(const bf16x8*)(sW + (wc * 64 + bg * 16 + r) * STR + xo);
          yacc[0][bg] = __builtin_amdgcn_mfma_f32_16x16x32_bf16(a0, bb, yacc[0][bg], 0, 0, 0);
          yacc[1][bg] = __builtin_amdgcn_mfma_f32_16x16x32_bf16(a1, bb, yacc[1][bg], 0, 0, 0);
        }
      }
    }
    __syncthreads();
    // write Y chunk to LDS as bf16: D layout col=lane&15, row=(lane>>4)*4+reg (HW-verified)
#pragma unroll
    for (int aj = 0; aj < 2; ++aj)
#pragma unroll
      for (int bg = 0; bg < 4; ++bg)
#pragma unroll
        for (int reg = 0; reg < 4; ++reg)
          sY[(wr * 32 + aj * 16 + h * 4 + reg) * STR + (wc * 64 + bg * 16 + r)] =
              f2bf(yacc[aj][bg][reg]);
    __syncthreads();
    // Z-GEMM partial: Z[i,j] += C[i,g] * Y[j,g], wave tile 32(i) x 64(j), K-chunk 128
#pragma unroll
    for (int ks = 0; ks < 4; ++ks) {
      const int go = ks * 32 + h * 8;
      bf16x8 a0 = *(const bf16x8*)(sC + (wr * 32 + 0  + r) * STR + go);
      bf16x8 a1 = *(const bf16x8*)(sC + (wr * 32 + 16 + r) * STR + go);
#pragma unroll
      for (int bj = 0; bj < 4; ++bj) {
        bf16x8 bb = *(const bf16x8*)(sY + (wc * 64 + bj * 16 + r) * STR + go);
        zacc[0][bj] = __builtin_amdgcn_mfma_f32_16x16x32_bf16(a0, bb, zacc[0][bj], 0, 0, 0);
        zacc[1][bj] = __builtin_amdgcn_mfma_f32_16x16x32_bf16(a1, bb, zacc[1][bj], 0, 0, 0);
      }
    }
  }
  __syncthreads();
  // dump Z to LDS fp32 (stride 132; overlays sX/sW which are no longer read)
#pragma unroll
  for (int ai = 0; ai < 2; ++ai)
#pragma unroll
    for (int bj = 0; bj < 4; ++bj)
#pragma unroll
      for (int reg = 0; reg < 4; ++reg)
        sZ[(wr * 32 + ai * 16 + h * 4 + reg) * 132 + (wc * 64 + bj * 16 + r)] =
            zacc[ai][bj][reg];
  __syncthreads();

  // per-row lse over j (128 cols); wave handles 16 rows, 4 lanes per row
  const int row = wave * 16 + (lane >> 2);
  const int c0  = lane & 3;
  float mx = -3.4e38f;
#pragma unroll
  for (int m = 0; m < 32; ++m) mx = fmaxf(mx, sZ[row * 132 + c0 + m * 4]);
  mx = fmaxf(mx, __shfl_xor(mx, 1));
  mx = fmaxf(mx, __shfl_xor(mx, 2));
  float sum = 0.f;
#pragma unroll
  for (int m = 0; m < 32; ++m) sum += __expf(sZ[row * 132 + c0 + m * 4] - mx);
  sum += __shfl_xor(sum, 1);
  sum += __shfl_xor(sum, 2);
  float val = (c0 == 0) ? (sZ[row * 132 + row] - (__logf(sum) + mx)) : 0.f;
#pragma unroll
  for (int off = 1; off < 64; off <<= 1) val += __shfl_xor(val, off);
  if (lane == 0) sRed[wave] = val;
  __syncthreads();
  if (tid == 0) {
    float bs = 0.f;
#pragma unroll
    for (int w2 = 0; w2 < 8; ++w2) bs += sRed[w2];
    atomicAdd(out + k, bs);
  }
}

extern "C" void kernel_launch(void* const* d_in, const int* in_sizes, int n_in,
                              void* d_out, int out_size, void* d_ws, size_t ws_size,
                              hipStream_t stream) {
  const float* C = (const float*)d_in[0];
  const float* X = (const float*)d_in[1];
  const float* W = (const float*)d_in[2];
  // d_in[3] (bias) intentionally unused: j-independent bias cancels in Zdiag - lse
  float* out = (float*)d_out;

  hipLaunchKernelGGL(zero4, dim3(1), dim3(64), 0, stream, out);
  hipLaunchKernelGGL(infonce_main, dim3(2047 * 4), dim3(512), 0, stream, C, X, W, out);
  hipLaunchKernelGGL(finalize4, dim3(1), dim3(64), 0, stream, out);
}

// Round 2
// 1733.313 us; speedup vs baseline: 1.2487x; 1.2487x over previous
//
#include <hip/hip_runtime.h>
#include <math.h>

// Problem constants
constexpr int Tn  = 2048;  // time
constexpr int FCn = 512;   // context feats (g)
constexpr int FXn = 512;   // encoding feats (x)
constexpr int SXW = 72;    // LDS stride (bf16 elems) for sX/sW chunks (64 + 8)
constexpr int SYC = 136;   // LDS stride (bf16 elems) for sY/sC (128 + 8)
constexpr int SZS = 132;   // LDS stride (fp32) for sZ

typedef __attribute__((ext_vector_type(8))) short  bf16x8;
typedef __attribute__((ext_vector_type(4))) float  f32x4;

// truncating fp32->bf16 pack: one v_perm_b32 per 2 elems
__device__ __forceinline__ unsigned pk2(float a, float b) {
  return __builtin_amdgcn_perm(__float_as_uint(b), __float_as_uint(a), 0x07060302u);
}
__device__ __forceinline__ uint4 pack8(float4 a, float4 b) {
  uint4 rv;
  rv.x = pk2(a.x, a.y); rv.y = pk2(a.z, a.w);
  rv.z = pk2(b.x, b.y); rv.w = pk2(b.z, b.w);
  return rv;
}

__global__ void zero4(float* out) {
  if (threadIdx.x < 4) out[threadIdx.x] = 0.0f;
}

__global__ void finalize4(float* out) {
  int k = threadIdx.x;
  if (k < 4) out[k] *= 1.0f / (128.0f * (float)(Tn - (1 << k)));
}

// One block per (k, t). Z[i,j] = sum_g C[i,t,g] * (sum_x W[k,g,x] X[j,t+tau,x])
// (bias dropped: j-independent bias cancels in Zdiag - lse), then row-lse and
// sum_i (Zdiag - lse) atomically accumulated into out[k].
__global__ __launch_bounds__(512, 4)
void infonce_main(const float* __restrict__ Cp, const float* __restrict__ Xp,
                  const float* __restrict__ Wp, float* __restrict__ out)
{
  // LDS: sX [128][72] | sW [128][72] | sY [128][136]  = 71680 B (2 blocks/CU)
  // sC overlays sX+sW; sZ (fp32 [128][132]) + sRed overlay everything.
  __shared__ __align__(16) unsigned char smem[71680];
  unsigned short* sX = (unsigned short*)(smem);
  unsigned short* sW = (unsigned short*)(smem + 18432);
  unsigned short* sY = (unsigned short*)(smem + 36864);
  unsigned short* sC = (unsigned short*)(smem);
  float* sZ   = (float*)(smem);
  float* sRed = (float*)(smem + 67584);

  const int tid  = threadIdx.x;
  const int lane = tid & 63;
  const int wave = tid >> 6;     // 0..7
  const int r    = lane & 15;
  const int h    = lane >> 4;    // 0..3
  const int wr   = wave >> 1;    // 0..3  (32-row group)
  const int wc   = wave & 1;     // 0..1  (64-col group)

  // bijective chunked XCD swizzle: nwg = 8188 = 8*1023 + 4 (q=1023, r=4)
  const int orig = blockIdx.x;
  const int xcd  = orig & 7;
  const int loc  = orig >> 3;
  const int wg   = (xcd < 4) ? (xcd * 1024 + loc) : (4096 + (xcd - 4) * 1023 + loc);
  const int k    = wg & 3;
  const int t    = wg >> 2;
  const int tau  = 1 << k;       // TAU = {1,2,4,8}
  if (t >= Tn - tau) return;     // uniform early-exit, before any barrier

  const float* Cb = Cp + (size_t)t * FCn;             // C[i,t,g] = Cb[i*Tn*FCn + g]
  const float* Xb = Xp + (size_t)(t + tau) * FXn;     // X[j,s,x] = Xb[j*Tn*FXn + x]
  const float* Wb = Wp + (size_t)k * (FCn * FXn);     // W[k,g,x]

  // staging coords: 4 threads per row, 16 elems each (64-col chunk)
  const int srow = tid >> 2;
  const int scol = (tid & 3) * 16;
  const float* xs = Xb + (size_t)srow * (Tn * FXn) + scol;
  const float* ws = Wb + (size_t)srow * FXn + scol;
  unsigned short* xd = sX + srow * SXW + scol;
  unsigned short* wd = sW + srow * SXW + scol;
  // C staging coords: 16 threads per row, 8 elems each, 32 rows per rep
  const int crow0 = tid >> 4;            // 0..31
  const int ccol  = (tid & 15) * 8;
  const float* cs = Cb + (size_t)crow0 * (Tn * FCn) + ccol;
  unsigned short* cd = sC + crow0 * SYC + ccol;

  f32x4 zacc[2][4];
#pragma unroll
  for (int a = 0; a < 2; ++a)
#pragma unroll
    for (int b = 0; b < 4; ++b) zacc[a][b] = f32x4{0.f, 0.f, 0.f, 0.f};

  for (int gc = 0; gc < 4; ++gc) {
    f32x4 yacc[2][4];
#pragma unroll
    for (int a = 0; a < 2; ++a)
#pragma unroll
      for (int b = 0; b < 4; ++b) yacc[a][b] = f32x4{0.f, 0.f, 0.f, 0.f};

    for (int xc = 0; xc < 8; ++xc) {
      // issue global loads EARLY (overlap prev phase's MFMA); LDS untouched here
      const int xo = xc * 64;
      float4 x0 = *(const float4*)(xs + xo);
      float4 x1 = *(const float4*)(xs + xo + 4);
      float4 x2 = *(const float4*)(xs + xo + 8);
      float4 x3 = *(const float4*)(xs + xo + 12);
      const size_t wo = (size_t)gc * 128 * FXn + xo;
      float4 w0 = *(const float4*)(ws + wo);
      float4 w1 = *(const float4*)(ws + wo + 4);
      float4 w2 = *(const float4*)(ws + wo + 8);
      float4 w3 = *(const float4*)(ws + wo + 12);
      __syncthreads();  // prev phase's LDS reads (Y/Z-MFMA) done before overwrite
      *(uint4*)(xd)     = pack8(x0, x1);
      *(uint4*)(xd + 8) = pack8(x2, x3);
      *(uint4*)(wd)     = pack8(w0, w1);
      *(uint4*)(wd + 8) = pack8(w2, w3);
      __syncthreads();
      // Y-GEMM: Y[j,g] += X[j,x] * W[g,x]; wave tile 32(j) x 64(g), K-chunk 64
#pragma unroll
      for (int ks = 0; ks < 2; ++ks) {
        const int xoo = ks * 32 + h * 8;
        bf16x8 a0 = *(const bf16x8*)(sX + (wr * 32 + 0  + r) * SXW + xoo);
        bf16x8 a1 = *(const bf16x8*)(sX + (wr * 32 + 16 + r) * SXW + xoo);
#pragma unroll
        for (int bg = 0; bg < 4; ++bg) {
          bf16x8 bb = *(const bf16x8*)(sW + (wc * 64 + bg * 16 + r) * SXW + xoo);
          yacc[0][bg] = __builtin_amdgcn_mfma_f32_16x16x32_bf16(a0, bb, yacc[0][bg], 0, 0, 0);
          yacc[1][bg] = __builtin_amdgcn_mfma_f32_16x16x32_bf16(a1, bb, yacc[1][bg], 0, 0, 0);
        }
      }
    }

    // issue C loads for this gc early (global only, no LDS hazard)
    float4 c0 = *(const float4*)(cs + 0 * 32 * (size_t)(Tn * FCn) + gc * 128);
    float4 c1 = *(const float4*)(cs + 0 * 32 * (size_t)(Tn * FCn) + gc * 128 + 4);
    float4 c2 = *(const float4*)(cs + 1 * 32 * (size_t)(Tn * FCn) + gc * 128);
    float4 c3 = *(const float4*)(cs + 1 * 32 * (size_t)(Tn * FCn) + gc * 128 + 4);
    float4 c4 = *(const float4*)(cs + 2 * 32 * (size_t)(Tn * FCn) + gc * 128);
    float4 c5 = *(const float4*)(cs + 2 * 32 * (size_t)(Tn * FCn) + gc * 128 + 4);
    float4 c6 = *(const float4*)(cs + 3 * 32 * (size_t)(Tn * FCn) + gc * 128);
    float4 c7 = *(const float4*)(cs + 3 * 32 * (size_t)(Tn * FCn) + gc * 128 + 4);

    // write Y chunk to sY as bf16 (D layout col=lane&15, row=(lane>>4)*4+reg)
#pragma unroll
    for (int aj = 0; aj < 2; ++aj)
#pragma unroll
      for (int bg = 0; bg < 4; ++bg)
#pragma unroll
        for (int reg = 0; reg < 4; ++reg)
          sY[(wr * 32 + aj * 16 + h * 4 + reg) * SYC + (wc * 64 + bg * 16 + r)] =
              (unsigned short)(__float_as_uint(yacc[aj][bg][reg]) >> 16);
    __syncthreads();  // all Y-MFMA reads of sX/sW done + sY writes visible
    // stage C chunk into sC (overlays sX/sW)
    *(uint4*)(cd + 0 * 32 * SYC) = pack8(c0, c1);
    *(uint4*)(cd + 1 * 32 * SYC) = pack8(c2, c3);
    *(uint4*)(cd + 2 * 32 * SYC) = pack8(c4, c5);
    *(uint4*)(cd + 3 * 32 * SYC) = pack8(c6, c7);
    __syncthreads();
    // Z-GEMM partial: Z[i,j] += C[i,g] * Y[j,g]; wave tile 32(i) x 64(j), K=128
#pragma unroll
    for (int ks = 0; ks < 4; ++ks) {
      const int go = ks * 32 + h * 8;
      bf16x8 a0 = *(const bf16x8*)(sC + (wr * 32 + 0  + r) * SYC + go);
      bf16x8 a1 = *(const bf16x8*)(sC + (wr * 32 + 16 + r) * SYC + go);
#pragma unroll
      for (int bj = 0; bj < 4; ++bj) {
        bf16x8 bb = *(const bf16x8*)(sY + (wc * 64 + bj * 16 + r) * SYC + go);
        zacc[0][bj] = __builtin_amdgcn_mfma_f32_16x16x32_bf16(a0, bb, zacc[0][bj], 0, 0, 0);
        zacc[1][bj] = __builtin_amdgcn_mfma_f32_16x16x32_bf16(a1, bb, zacc[1][bj], 0, 0, 0);
      }
    }
  }
  __syncthreads();  // all Z-MFMA LDS reads done before sZ overlay
  // dump Z to LDS fp32 (stride 132)
#pragma unroll
  for (int ai = 0; ai < 2; ++ai)
#pragma unroll
    for (int bj = 0; bj < 4; ++bj)
#pragma unroll
      for (int reg = 0; reg < 4; ++reg)
        sZ[(wr * 32 + ai * 16 + h * 4 + reg) * SZS + (wc * 64 + bj * 16 + r)] =
            zacc[ai][bj][reg];
  __syncthreads();

  // per-row lse over j (128 cols); wave handles 16 rows, 4 lanes per row
  const int row = wave * 16 + (lane >> 2);
  const int c0l = lane & 3;
  float mx = -3.4e38f;
#pragma unroll
  for (int m = 0; m < 32; ++m) mx = fmaxf(mx, sZ[row * SZS + c0l + m * 4]);
  mx = fmaxf(mx, __shfl_xor(mx, 1));
  mx = fmaxf(mx, __shfl_xor(mx, 2));
  float sum = 0.f;
#pragma unroll
  for (int m = 0; m < 32; ++m) sum += __expf(sZ[row * SZS + c0l + m * 4] - mx);
  sum += __shfl_xor(sum, 1);
  sum += __shfl_xor(sum, 2);
  float val = (c0l == 0) ? (sZ[row * SZS + row] - (__logf(sum) + mx)) : 0.f;
#pragma unroll
  for (int off = 1; off < 64; off <<= 1) val += __shfl_xor(val, off);
  if (lane == 0) sRed[wave] = val;
  __syncthreads();
  if (tid == 0) {
    float bs = 0.f;
#pragma unroll
    for (int w2 = 0; w2 < 8; ++w2) bs += sRed[w2];
    atomicAdd(out + k, bs);
  }
}

extern "C" void kernel_launch(void* const* d_in, const int* in_sizes, int n_in,
                              void* d_out, int out_size, void* d_ws, size_t ws_size,
                              hipStream_t stream) {
  const float* C = (const float*)d_in[0];
  const float* X = (const float*)d_in[1];
  const float* W = (const float*)d_in[2];
  // d_in[3] (bias) intentionally unused: j-independent bias cancels in Zdiag - lse
  float* out = (float*)d_out;

  hipLaunchKernelGGL(zero4, dim3(1), dim3(64), 0, stream, out);
  hipLaunchKernelGGL(infonce_main, dim3(2047 * 4), dim3(512), 0, stream, C, X, W, out);
  hipLaunchKernelGGL(finalize4, dim3(1), dim3(64), 0, stream, out);
}